// Round 7
// baseline (209.921 us; speedup 1.0000x reference)
//
#include <hip/hip_runtime.h>
#include <hip/hip_bf16.h>
#include <math.h>

#define BROWS 4096
#define DIM   512
#define YEMB_E 2097152   // 4096*512, element offset of emb rows in Y
#define TSTRIDE 127      // tile stride (tiles are 128 wide, overlap by 1)
#define NT 33            // tiles per dim; triangle blocks = 33*34/2 = 561

typedef float f32x4 __attribute__((ext_vector_type(4)));
typedef __bf16 bf16x8 __attribute__((ext_vector_type(8)));
typedef _Float16 f16x4 __attribute__((ext_vector_type(4)));

// ---------------------------------------------------------------------------
// prep3: wave-per-row, no barriers. 8192 rows (low then emb), 4 rows/block.
// ---------------------------------------------------------------------------
__global__ __launch_bounds__(256) void prep3_kernel(
    const float* __restrict__ low, const float* __restrict__ emb,
    __hip_bfloat16* __restrict__ Y,
    float* __restrict__ s_l, float* __restrict__ r_l,
    float* __restrict__ s_e, float* __restrict__ r_e,
    float* __restrict__ out) {
  const int tid = threadIdx.x;
  const int lane = tid & 63, wid = tid >> 6;
  const int rid = blockIdx.x * 4 + wid;          // 0..8191
  if (blockIdx.x == 0 && tid == 0) out[0] = 0.f;

  const bool is_low = (rid < BROWS);
  const int row = is_low ? rid : rid - BROWS;
  const float* x = (is_low ? low : emb) + (size_t)row * DIM;

  const float4 v0 = ((const float4*)x)[lane * 2];
  const float4 v1 = ((const float4*)x)[lane * 2 + 1];

  float ss = v0.x * v0.x + v0.y * v0.y + v0.z * v0.z + v0.w * v0.w +
             v1.x * v1.x + v1.y * v1.y + v1.z * v1.z + v1.w * v1.w;
#pragma unroll
  for (int o = 1; o < 64; o <<= 1) ss += __shfl_xor(ss, o, 64);
  const float inv = 1.0f / fmaxf(sqrtf(ss), 1e-12f);

  float y[8] = {v0.x * inv, v0.y * inv, v0.z * inv, v0.w * inv,
                v1.x * inv, v1.y * inv, v1.z * inv, v1.w * inv};

  union { __hip_bfloat16 h[8]; uint4 u4; } pk;
  float sv = 0.f, rv = 0.f;
#pragma unroll
  for (int i = 0; i < 8; ++i) {
    pk.h[i] = __float2bfloat16(y[i]);
    sv += y[i] * y[i];
    rv += y[i];
  }
  ((uint4*)(Y + (size_t)rid * DIM))[lane] = pk.u4;

#pragma unroll
  for (int o = 1; o < 64; o <<= 1) {
    sv += __shfl_xor(sv, o, 64);
    rv += __shfl_xor(rv, o, 64);
  }
  if (lane == 0) {
    (is_low ? s_l : s_e)[row] = sv;
    (is_low ? r_l : r_e)[row] = rv;
  }
}

// ---------------------------------------------------------------------------
// Symmetric fused MFMA kernel, round 7: sequential matrices, low regs.
// Grid: 561 blocks 1D -> (br,bc) upper triangle, tile 128x128 (stride 127).
// 4 waves 2x2, wave tile 64x64, ONE matrix at a time: acc = 64 AGPR.
// Phase m=0 (low): K-loop -> distances -> packed f16 (32 VGPR).
// Phase m=1 (emb): same K-loop reusing acc -> de stays f32 in acc.
// K-loop: BK=64, 8 iters/phase, stage A(128)+B(128) rows = 32 KB via
//   global_load_lds w=16. K-chunk XOR-swizzled by row&7 on the GLOBAL
//   address side (LDS stays linear-in-lane per the wave-uniform-base rule)
//   so BK=64 frag reads are bank-conflict-free.
// Epilogue: R6-proven direct + transposed pair terms (dl from f16 unpack).
// C frag mapping (m89/m91): col(j)=lane&15, row(i)=(lane>>4)*4+reg.
// ---------------------------------------------------------------------------
__global__ __launch_bounds__(256, 4) void fused_sym_kernel(
    const __hip_bfloat16* __restrict__ Y,
    const float* __restrict__ s_l, const float* __restrict__ r_l,
    const float* __restrict__ s_e, const float* __restrict__ r_e,
    float* __restrict__ out) {
  __shared__ __align__(16) __hip_bfloat16 lds[16384];  // 32 KB staging
  __shared__ float hand_d[2][64][2];
  __shared__ float hand_t[2][64][2];
  __shared__ float sred[4];

  // decode upper-triangle block id
  int rem = blockIdx.x, br = 0;
  while (rem >= NT - br) { rem -= NT - br; ++br; }
  const int bc = br + rem;

  const int tid = threadIdx.x;
  const int lane = tid & 63;
  const int wid = tid >> 6;
  const int wr = wid >> 1, wc = wid & 1;
  const int quad = lane >> 4, cpos = lane & 15;
  const int sw = cpos & 7;
  const int r0 = br * TSTRIDE, c0 = bc * TSTRIDE;

  // staging: 2048 slots of 16B; thread owns slot = tid + 256*s.
  // slot<1024: A local row slot>>3; else B local col (slot-1024)>>3.
  // global K-chunk = (slot&7) ^ (localrow&7)  [swizzle].
  int goff[8];
#pragma unroll
  for (int s = 0; s < 8; ++s) {
    const int c = tid + 256 * s;
    int o;
    if (c < 1024) {
      const int row = c >> 3;
      o = min(r0 + row, BROWS - 1) * DIM + (((c & 7) ^ (row & 7)) << 3);
    } else {
      const int c2 = c - 1024;
      const int col = c2 >> 3;
      o = min(c0 + col, BROWS - 1) * DIM + (((c2 & 7) ^ (col & 7)) << 3);
    }
    goff[s] = o;
  }

  // frag base offsets (elems); per-read chunk = base + ((kk*4+quad)^sw)*8
  int abase[4], bbase[4];
#pragma unroll
  for (int u = 0; u < 4; ++u) abase[u] = (64 * wr + 16 * u + cpos) * 64;
#pragma unroll
  for (int v = 0; v < 4; ++v) bbase[v] = 8192 + (64 * wc + 16 * v + cpos) * 64;

  const float epst = (float)DIM * 1e-6f * 1e-6f;
  f32x4 acc[4][4];
  f16x4 dlh[4][4];

#pragma unroll
  for (int m = 0; m < 2; ++m) {
    const __hip_bfloat16* Ym = Y + m * YEMB_E;
#pragma unroll
    for (int u = 0; u < 4; ++u)
#pragma unroll
      for (int v = 0; v < 4; ++v) acc[u][v] = (f32x4)(0.f);

    for (int it = 0; it < 8; ++it) {
      const int k0 = it * 64;
#pragma unroll
      for (int s = 0; s < 8; ++s)
        __builtin_amdgcn_global_load_lds(
            (const __attribute__((address_space(1))) void*)(Ym + goff[s] + k0),
            (__attribute__((address_space(3))) void*)(lds + (tid + 256 * s) * 8),
            16, 0, 0);
      __syncthreads();

#pragma unroll
      for (int kk = 0; kk < 2; ++kk) {
        bf16x8 a[4], b[4];
#pragma unroll
        for (int u = 0; u < 4; ++u)
          a[u] = *(const bf16x8*)&lds[abase[u] + (((kk * 4 + quad) ^ sw) << 3)];
#pragma unroll
        for (int v = 0; v < 4; ++v)
          b[v] = *(const bf16x8*)&lds[bbase[v] + (((kk * 4 + quad) ^ sw) << 3)];
#pragma unroll
        for (int u = 0; u < 4; ++u)
#pragma unroll
          for (int v = 0; v < 4; ++v)
            acc[u][v] = __builtin_amdgcn_mfma_f32_16x16x32_bf16(
                a[u], b[v], acc[u][v], 0, 0, 0);
      }
      __syncthreads();
    }

    // transform acc -> distances for this matrix
    const float* sp = m ? s_e : s_l;
    const float* rp = m ? r_e : r_l;
#pragma unroll
    for (int v = 0; v < 4; ++v) {
      const int j = min(c0 + 64 * wc + 16 * v + cpos, BROWS - 1);
      const float sj = sp[j], rj = rp[j];
#pragma unroll
      for (int u = 0; u < 4; ++u) {
        float d[4];
#pragma unroll
        for (int r = 0; r < 4; ++r) {
          const int i = min(r0 + 64 * wr + 16 * u + 4 * quad + r, BROWS - 1);
          const float sq = sp[i] + sj - 2.f * acc[u][v][r] +
                           2e-6f * (rp[i] - rj) + epst;
          d[r] = sqrtf(fmaxf(sq, 0.f));
        }
        if (m == 0) {
          dlh[u][v] = (f16x4){(_Float16)d[0], (_Float16)d[1],
                              (_Float16)d[2], (_Float16)d[3]};
        } else {
          acc[u][v] = (f32x4){d[0], d[1], d[2], d[3]};
        }
      }
    }
  }
  // now: dl (f16) in dlh, de (f32) in acc

  // ---- publish cross-wave boundary values ----
  if (wc == 1 && cpos == 0) {   // tile col 64, all 64 local rows
#pragma unroll
    for (int u = 0; u < 4; ++u)
#pragma unroll
      for (int r = 0; r < 4; ++r) {
        hand_d[wr][16 * u + 4 * quad + r][0] = (float)dlh[u][0][r];
        hand_d[wr][16 * u + 4 * quad + r][1] = acc[u][0][r];
      }
  }
  if (wr == 1 && quad == 0) {   // tile row 64, all 64 local cols
#pragma unroll
    for (int v = 0; v < 4; ++v) {
      hand_t[wc][16 * v + cpos][0] = (float)dlh[0][v][0];
      hand_t[wc][16 * v + cpos][1] = acc[0][v][0];
    }
  }
  __syncthreads();

  float sum = 0.f;

  // ---- pass 1: direct terms (i in rows, pair cols j,j+1) ----
  const int srcin = (lane & 48) | ((cpos + 1) & 15);
#pragma unroll
  for (int u = 0; u < 4; ++u)
#pragma unroll
    for (int r = 0; r < 4; ++r) {
      const int trow = 64 * wr + 16 * u + 4 * quad + r;
      const int i = r0 + trow;
      const bool rowok = (trow <= 126) && (i <= BROWS - 2);
#pragma unroll
      for (int v = 0; v < 4; ++v) {
        const float dl1 = (float)dlh[u][v][r], de1 = acc[u][v][r];
        float dl2 = __shfl(dl1, srcin, 64);
        float de2 = __shfl(de1, srcin, 64);
        if (v < 3) {
          const float dlb = __shfl((float)dlh[u][v + 1][r], lane & 48, 64);
          const float deb = __shfl(acc[u][v + 1][r], lane & 48, 64);
          if (cpos == 15) { dl2 = dlb; de2 = deb; }
        } else if (cpos == 15 && wc == 0) {
          dl2 = hand_d[wr][16 * u + 4 * quad + r][0];
          de2 = hand_d[wr][16 * u + 4 * quad + r][1];
        }
        const int tcol = 64 * wc + 16 * v + cpos;
        const int j = c0 + tcol;
        if (rowok && tcol <= 126 && j <= BROWS - 3) {
          const float aa = dl1 - dl2, bb = de1 - de2;
          const float coeff = (float)((aa > 0.f) - (aa < 0.f)) -
                              (float)((bb > 0.f) - (bb < 0.f));
          sum += coeff * (de2 - de1);
        }
      }
    }

  // ---- pass 2: transposed terms (i in cols, pair rows j,j+1), off-diag only ----
  if (br != bc) {
#pragma unroll
    for (int u = 0; u < 4; ++u)
#pragma unroll
      for (int v = 0; v < 4; ++v) {
        const int tcol = 64 * wc + 16 * v + cpos;
        const int ii = c0 + tcol;
        const bool colok = (tcol <= 126) && (ii <= BROWS - 2);
        const float dlv[4] = {(float)dlh[u][v][0], (float)dlh[u][v][1],
                              (float)dlh[u][v][2], (float)dlh[u][v][3]};
#pragma unroll
        for (int r = 0; r < 3; ++r) {
          const int trow = 64 * wr + 16 * u + 4 * quad + r;
          const int jj = r0 + trow;
          if (colok && trow <= 126 && jj <= BROWS - 3) {
            const float aa = dlv[r] - dlv[r + 1];
            const float bb = acc[u][v][r] - acc[u][v][r + 1];
            const float coeff = (float)((aa > 0.f) - (aa < 0.f)) -
                                (float)((bb > 0.f) - (bb < 0.f));
            sum += coeff * (acc[u][v][r + 1] - acc[u][v][r]);
          }
        }
        {  // r == 3 boundary: next row lives in another quad/u/wave
          const int trow = 64 * wr + 16 * u + 4 * quad + 3;
          const int jj = r0 + trow;
          const float dlq = __shfl(dlv[0], (lane + 16) & 63, 64);
          const float deq = __shfl(acc[u][v][0], (lane + 16) & 63, 64);
          const int un = (u < 3) ? u + 1 : u;
          const float dlu = __shfl((float)dlh[un][v][0], cpos, 64);
          const float deu = __shfl(acc[un][v][0], cpos, 64);
          float dl2, de2;
          if (quad < 3)      { dl2 = dlq; de2 = deq; }
          else if (u < 3)    { dl2 = dlu; de2 = deu; }
          else               { dl2 = hand_t[wc][16 * v + cpos][0];
                               de2 = hand_t[wc][16 * v + cpos][1]; }
          if (colok && trow <= 126 && jj <= BROWS - 3) {
            const float dl1 = dlv[3], de1 = acc[u][v][3];
            const float aa = dl1 - dl2, bb = de1 - de2;
            const float coeff = (float)((aa > 0.f) - (aa < 0.f)) -
                                (float)((bb > 0.f) - (bb < 0.f));
            sum += coeff * (de2 - de1);
          }
        }
      }
  }

  // ---- reduce + atomic ----
#pragma unroll
  for (int o = 32; o; o >>= 1) sum += __shfl_down(sum, o, 64);
  if (lane == 0) sred[wid] = sum;
  __syncthreads();
  if (tid == 0) {
    const float scale = 1.0f / ((float)(BROWS - 1) * (float)(BROWS - 2));
    atomicAdd(out, (sred[0] + sred[1] + sred[2] + sred[3]) * scale);
  }
}

// ===========================================================================
extern "C" void kernel_launch(void* const* d_in, const int* in_sizes, int n_in,
                              void* d_out, int out_size, void* d_ws,
                              size_t ws_size, hipStream_t stream) {
  const float* low = (const float*)d_in[0];
  const float* emb = (const float*)d_in[1];
  float* out = (float*)d_out;

  // ws: Y (2*4096*512 bf16 = 8 MB) then s_l, r_l, s_e, r_e (4096 f32 each)
  __hip_bfloat16* Y = (__hip_bfloat16*)d_ws;
  float* s_l = (float*)(Y + 2 * (size_t)BROWS * DIM);
  float* r_l = s_l + BROWS;
  float* s_e = r_l + BROWS;
  float* r_e = s_e + BROWS;

  prep3_kernel<<<2 * BROWS / 4, 256, 0, stream>>>(low, emb, Y, s_l, r_l, s_e, r_e, out);
  fused_sym_kernel<<<NT * (NT + 1) / 2, 256, 0, stream>>>(Y, s_l, r_l, s_e, r_e, out);
}

// Round 8
// 171.438 us; speedup vs baseline: 1.2245x; 1.2245x over previous
//
#include <hip/hip_runtime.h>
#include <hip/hip_bf16.h>
#include <math.h>

#define BROWS 4096
#define DIM   512
#define YEMB_E 2097152   // 4096*512, element offset of emb rows in Y
#define TSTRIDE 127      // tile stride (tiles are 128 wide, overlap by 1)
#define NT 33            // tiles per dim; triangle blocks = 33*34/2 = 561

typedef float f32x4 __attribute__((ext_vector_type(4)));
typedef __bf16 bf16x8 __attribute__((ext_vector_type(8)));
typedef _Float16 f16x4 __attribute__((ext_vector_type(4)));

// ---------------------------------------------------------------------------
// prep3: wave-per-row, no barriers. 8192 rows (low then emb), 4 rows/block.
// ---------------------------------------------------------------------------
__global__ __launch_bounds__(256) void prep3_kernel(
    const float* __restrict__ low, const float* __restrict__ emb,
    __hip_bfloat16* __restrict__ Y,
    float* __restrict__ s_l, float* __restrict__ r_l,
    float* __restrict__ s_e, float* __restrict__ r_e,
    float* __restrict__ out) {
  const int tid = threadIdx.x;
  const int lane = tid & 63, wid = tid >> 6;
  const int rid = blockIdx.x * 4 + wid;          // 0..8191
  if (blockIdx.x == 0 && tid == 0) out[0] = 0.f;

  const bool is_low = (rid < BROWS);
  const int row = is_low ? rid : rid - BROWS;
  const float* x = (is_low ? low : emb) + (size_t)row * DIM;

  const float4 v0 = ((const float4*)x)[lane * 2];
  const float4 v1 = ((const float4*)x)[lane * 2 + 1];

  float ss = v0.x * v0.x + v0.y * v0.y + v0.z * v0.z + v0.w * v0.w +
             v1.x * v1.x + v1.y * v1.y + v1.z * v1.z + v1.w * v1.w;
#pragma unroll
  for (int o = 1; o < 64; o <<= 1) ss += __shfl_xor(ss, o, 64);
  const float inv = 1.0f / fmaxf(sqrtf(ss), 1e-12f);

  float y[8] = {v0.x * inv, v0.y * inv, v0.z * inv, v0.w * inv,
                v1.x * inv, v1.y * inv, v1.z * inv, v1.w * inv};

  union { __hip_bfloat16 h[8]; uint4 u4; } pk;
  float sv = 0.f, rv = 0.f;
#pragma unroll
  for (int i = 0; i < 8; ++i) {
    pk.h[i] = __float2bfloat16(y[i]);
    sv += y[i] * y[i];
    rv += y[i];
  }
  ((uint4*)(Y + (size_t)rid * DIM))[lane] = pk.u4;

#pragma unroll
  for (int o = 1; o < 64; o <<= 1) {
    sv += __shfl_xor(sv, o, 64);
    rv += __shfl_xor(rv, o, 64);
  }
  if (lane == 0) {
    (is_low ? s_l : s_e)[row] = sv;
    (is_low ? r_l : r_e)[row] = rv;
  }
}

// ---------------------------------------------------------------------------
// Symmetric fused MFMA kernel, round 8 = round 7 with the register cap
// fixed: __launch_bounds__(256,3) -> 170-reg budget (kernel needs ~164).
// R7's (256,4)=128-reg cap caused 366 MB/launch of scratch spill traffic
// (WRITE_SIZE 205 MB, FETCH +104 MB) — the entire regression.
// Grid: 561 blocks 1D -> (br,bc) upper triangle, tile 128x128 (stride 127).
// 4 waves 2x2, wave tile 64x64, ONE matrix at a time: acc = 64 AGPR.
// Phase m=0 (low): K-loop -> distances -> packed f16 (32 VGPR).
// Phase m=1 (emb): same K-loop reusing acc -> de stays f32 in acc.
// K-loop: BK=64, 8 iters/phase, stage A(128)+B(128) rows = 32 KB via
//   global_load_lds w=16; K-chunk XOR-swizzled by row&7 on the GLOBAL
//   address side -> zero bank conflicts (verified R7: SQ_LDS_BANK_CONFLICT=0).
// C frag mapping (m89/m91): col(j)=lane&15, row(i)=(lane>>4)*4+reg.
// ---------------------------------------------------------------------------
__global__ __launch_bounds__(256, 3) void fused_sym_kernel(
    const __hip_bfloat16* __restrict__ Y,
    const float* __restrict__ s_l, const float* __restrict__ r_l,
    const float* __restrict__ s_e, const float* __restrict__ r_e,
    float* __restrict__ out) {
  __shared__ __align__(16) __hip_bfloat16 lds[16384];  // 32 KB staging
  __shared__ float hand_d[2][64][2];
  __shared__ float hand_t[2][64][2];
  __shared__ float sred[4];

  // decode upper-triangle block id
  int rem = blockIdx.x, br = 0;
  while (rem >= NT - br) { rem -= NT - br; ++br; }
  const int bc = br + rem;

  const int tid = threadIdx.x;
  const int lane = tid & 63;
  const int wid = tid >> 6;
  const int wr = wid >> 1, wc = wid & 1;
  const int quad = lane >> 4, cpos = lane & 15;
  const int sw = cpos & 7;
  const int r0 = br * TSTRIDE, c0 = bc * TSTRIDE;

  // staging: 2048 slots of 16B; thread owns slot = tid + 256*s.
  // slot<1024: A local row slot>>3; else B local col (slot-1024)>>3.
  // global K-chunk = (slot&7) ^ (localrow&7)  [swizzle].
  int goff[8];
#pragma unroll
  for (int s = 0; s < 8; ++s) {
    const int c = tid + 256 * s;
    int o;
    if (c < 1024) {
      const int row = c >> 3;
      o = min(r0 + row, BROWS - 1) * DIM + (((c & 7) ^ (row & 7)) << 3);
    } else {
      const int c2 = c - 1024;
      const int col = c2 >> 3;
      o = min(c0 + col, BROWS - 1) * DIM + (((c2 & 7) ^ (col & 7)) << 3);
    }
    goff[s] = o;
  }

  // frag base offsets (elems); per-read chunk = base + ((kk*4+quad)^sw)*8
  int abase[4], bbase[4];
#pragma unroll
  for (int u = 0; u < 4; ++u) abase[u] = (64 * wr + 16 * u + cpos) * 64;
#pragma unroll
  for (int v = 0; v < 4; ++v) bbase[v] = 8192 + (64 * wc + 16 * v + cpos) * 64;

  const float epst = (float)DIM * 1e-6f * 1e-6f;
  f32x4 acc[4][4];
  f16x4 dlh[4][4];

#pragma unroll
  for (int m = 0; m < 2; ++m) {
    const __hip_bfloat16* Ym = Y + m * YEMB_E;
#pragma unroll
    for (int u = 0; u < 4; ++u)
#pragma unroll
      for (int v = 0; v < 4; ++v) acc[u][v] = (f32x4)(0.f);

    for (int it = 0; it < 8; ++it) {
      const int k0 = it * 64;
#pragma unroll
      for (int s = 0; s < 8; ++s)
        __builtin_amdgcn_global_load_lds(
            (const __attribute__((address_space(1))) void*)(Ym + goff[s] + k0),
            (__attribute__((address_space(3))) void*)(lds + (tid + 256 * s) * 8),
            16, 0, 0);
      __syncthreads();

#pragma unroll
      for (int kk = 0; kk < 2; ++kk) {
        bf16x8 a[4], b[4];
#pragma unroll
        for (int u = 0; u < 4; ++u)
          a[u] = *(const bf16x8*)&lds[abase[u] + (((kk * 4 + quad) ^ sw) << 3)];
#pragma unroll
        for (int v = 0; v < 4; ++v)
          b[v] = *(const bf16x8*)&lds[bbase[v] + (((kk * 4 + quad) ^ sw) << 3)];
#pragma unroll
        for (int u = 0; u < 4; ++u)
#pragma unroll
          for (int v = 0; v < 4; ++v)
            acc[u][v] = __builtin_amdgcn_mfma_f32_16x16x32_bf16(
                a[u], b[v], acc[u][v], 0, 0, 0);
      }
      __syncthreads();
    }

    // transform acc -> distances for this matrix
    const float* sp = m ? s_e : s_l;
    const float* rp = m ? r_e : r_l;
#pragma unroll
    for (int v = 0; v < 4; ++v) {
      const int j = min(c0 + 64 * wc + 16 * v + cpos, BROWS - 1);
      const float sj = sp[j], rj = rp[j];
#pragma unroll
      for (int u = 0; u < 4; ++u) {
        float d[4];
#pragma unroll
        for (int r = 0; r < 4; ++r) {
          const int i = min(r0 + 64 * wr + 16 * u + 4 * quad + r, BROWS - 1);
          const float sq = sp[i] + sj - 2.f * acc[u][v][r] +
                           2e-6f * (rp[i] - rj) + epst;
          d[r] = sqrtf(fmaxf(sq, 0.f));
        }
        if (m == 0) {
          dlh[u][v] = (f16x4){(_Float16)d[0], (_Float16)d[1],
                              (_Float16)d[2], (_Float16)d[3]};
        } else {
          acc[u][v] = (f32x4){d[0], d[1], d[2], d[3]};
        }
      }
    }
  }
  // now: dl (f16) in dlh, de (f32) in acc

  // ---- publish cross-wave boundary values ----
  if (wc == 1 && cpos == 0) {   // tile col 64, all 64 local rows
#pragma unroll
    for (int u = 0; u < 4; ++u)
#pragma unroll
      for (int r = 0; r < 4; ++r) {
        hand_d[wr][16 * u + 4 * quad + r][0] = (float)dlh[u][0][r];
        hand_d[wr][16 * u + 4 * quad + r][1] = acc[u][0][r];
      }
  }
  if (wr == 1 && quad == 0) {   // tile row 64, all 64 local cols
#pragma unroll
    for (int v = 0; v < 4; ++v) {
      hand_t[wc][16 * v + cpos][0] = (float)dlh[0][v][0];
      hand_t[wc][16 * v + cpos][1] = acc[0][v][0];
    }
  }
  __syncthreads();

  float sum = 0.f;

  // ---- pass 1: direct terms (i in rows, pair cols j,j+1) ----
  const int srcin = (lane & 48) | ((cpos + 1) & 15);
#pragma unroll
  for (int u = 0; u < 4; ++u)
#pragma unroll
    for (int r = 0; r < 4; ++r) {
      const int trow = 64 * wr + 16 * u + 4 * quad + r;
      const int i = r0 + trow;
      const bool rowok = (trow <= 126) && (i <= BROWS - 2);
#pragma unroll
      for (int v = 0; v < 4; ++v) {
        const float dl1 = (float)dlh[u][v][r], de1 = acc[u][v][r];
        float dl2 = __shfl(dl1, srcin, 64);
        float de2 = __shfl(de1, srcin, 64);
        if (v < 3) {
          const float dlb = __shfl((float)dlh[u][v + 1][r], lane & 48, 64);
          const float deb = __shfl(acc[u][v + 1][r], lane & 48, 64);
          if (cpos == 15) { dl2 = dlb; de2 = deb; }
        } else if (cpos == 15 && wc == 0) {
          dl2 = hand_d[wr][16 * u + 4 * quad + r][0];
          de2 = hand_d[wr][16 * u + 4 * quad + r][1];
        }
        const int tcol = 64 * wc + 16 * v + cpos;
        const int j = c0 + tcol;
        if (rowok && tcol <= 126 && j <= BROWS - 3) {
          const float aa = dl1 - dl2, bb = de1 - de2;
          const float coeff = (float)((aa > 0.f) - (aa < 0.f)) -
                              (float)((bb > 0.f) - (bb < 0.f));
          sum += coeff * (de2 - de1);
        }
      }
    }

  // ---- pass 2: transposed terms (i in cols, pair rows j,j+1), off-diag only ----
  if (br != bc) {
#pragma unroll
    for (int u = 0; u < 4; ++u)
#pragma unroll
      for (int v = 0; v < 4; ++v) {
        const int tcol = 64 * wc + 16 * v + cpos;
        const int ii = c0 + tcol;
        const bool colok = (tcol <= 126) && (ii <= BROWS - 2);
        const float dlv[4] = {(float)dlh[u][v][0], (float)dlh[u][v][1],
                              (float)dlh[u][v][2], (float)dlh[u][v][3]};
#pragma unroll
        for (int r = 0; r < 3; ++r) {
          const int trow = 64 * wr + 16 * u + 4 * quad + r;
          const int jj = r0 + trow;
          if (colok && trow <= 126 && jj <= BROWS - 3) {
            const float aa = dlv[r] - dlv[r + 1];
            const float bb = acc[u][v][r] - acc[u][v][r + 1];
            const float coeff = (float)((aa > 0.f) - (aa < 0.f)) -
                                (float)((bb > 0.f) - (bb < 0.f));
            sum += coeff * (acc[u][v][r + 1] - acc[u][v][r]);
          }
        }
        {  // r == 3 boundary: next row lives in another quad/u/wave
          const int trow = 64 * wr + 16 * u + 4 * quad + 3;
          const int jj = r0 + trow;
          const float dlq = __shfl(dlv[0], (lane + 16) & 63, 64);
          const float deq = __shfl(acc[u][v][0], (lane + 16) & 63, 64);
          const int un = (u < 3) ? u + 1 : u;
          const float dlu = __shfl((float)dlh[un][v][0], cpos, 64);
          const float deu = __shfl(acc[un][v][0], cpos, 64);
          float dl2, de2;
          if (quad < 3)      { dl2 = dlq; de2 = deq; }
          else if (u < 3)    { dl2 = dlu; de2 = deu; }
          else               { dl2 = hand_t[wc][16 * v + cpos][0];
                               de2 = hand_t[wc][16 * v + cpos][1]; }
          if (colok && trow <= 126 && jj <= BROWS - 3) {
            const float dl1 = dlv[3], de1 = acc[u][v][3];
            const float aa = dl1 - dl2, bb = de1 - de2;
            const float coeff = (float)((aa > 0.f) - (aa < 0.f)) -
                                (float)((bb > 0.f) - (bb < 0.f));
            sum += coeff * (de2 - de1);
          }
        }
      }
  }

  // ---- reduce + atomic ----
#pragma unroll
  for (int o = 32; o; o >>= 1) sum += __shfl_down(sum, o, 64);
  if (lane == 0) sred[wid] = sum;
  __syncthreads();
  if (tid == 0) {
    const float scale = 1.0f / ((float)(BROWS - 1) * (float)(BROWS - 2));
    atomicAdd(out, (sred[0] + sred[1] + sred[2] + sred[3]) * scale);
  }
}

// ===========================================================================
extern "C" void kernel_launch(void* const* d_in, const int* in_sizes, int n_in,
                              void* d_out, int out_size, void* d_ws,
                              size_t ws_size, hipStream_t stream) {
  const float* low = (const float*)d_in[0];
  const float* emb = (const float*)d_in[1];
  float* out = (float*)d_out;

  // ws: Y (2*4096*512 bf16 = 8 MB) then s_l, r_l, s_e, r_e (4096 f32 each)
  __hip_bfloat16* Y = (__hip_bfloat16*)d_ws;
  float* s_l = (float*)(Y + 2 * (size_t)BROWS * DIM);
  float* r_l = s_l + BROWS;
  float* s_e = r_l + BROWS;
  float* r_e = s_e + BROWS;

  prep3_kernel<<<2 * BROWS / 4, 256, 0, stream>>>(low, emb, Y, s_l, r_l, s_e, r_e, out);
  fused_sym_kernel<<<NT * (NT + 1) / 2, 256, 0, stream>>>(Y, s_l, r_l, s_e, r_e, out);
}

// Round 9
// 137.407 us; speedup vs baseline: 1.5277x; 1.2477x over previous
//
#include <hip/hip_runtime.h>
#include <hip/hip_bf16.h>
#include <math.h>

#define BROWS 4096
#define DIM   512
#define YEMB_E 2097152   // 4096*512, element offset of emb rows in Y
#define TSTRIDE 127      // tile stride (tiles are 128 wide, overlap by 1)
#define NT 33            // tiles per dim; triangle blocks = 33*34/2 = 561

typedef float f32x4 __attribute__((ext_vector_type(4)));
typedef __bf16 bf16x8 __attribute__((ext_vector_type(8)));
typedef _Float16 f16x4 __attribute__((ext_vector_type(4)));

// ---------------------------------------------------------------------------
// prep3: wave-per-row, no barriers. 8192 rows (low then emb), 4 rows/block.
// ---------------------------------------------------------------------------
__global__ __launch_bounds__(256) void prep3_kernel(
    const float* __restrict__ low, const float* __restrict__ emb,
    __hip_bfloat16* __restrict__ Y,
    float* __restrict__ s_l, float* __restrict__ r_l,
    float* __restrict__ s_e, float* __restrict__ r_e,
    float* __restrict__ out) {
  const int tid = threadIdx.x;
  const int lane = tid & 63, wid = tid >> 6;
  const int rid = blockIdx.x * 4 + wid;          // 0..8191
  if (blockIdx.x == 0 && tid == 0) out[0] = 0.f;

  const bool is_low = (rid < BROWS);
  const int row = is_low ? rid : rid - BROWS;
  const float* x = (is_low ? low : emb) + (size_t)row * DIM;

  const float4 v0 = ((const float4*)x)[lane * 2];
  const float4 v1 = ((const float4*)x)[lane * 2 + 1];

  float ss = v0.x * v0.x + v0.y * v0.y + v0.z * v0.z + v0.w * v0.w +
             v1.x * v1.x + v1.y * v1.y + v1.z * v1.z + v1.w * v1.w;
#pragma unroll
  for (int o = 1; o < 64; o <<= 1) ss += __shfl_xor(ss, o, 64);
  const float inv = 1.0f / fmaxf(sqrtf(ss), 1e-12f);

  float y[8] = {v0.x * inv, v0.y * inv, v0.z * inv, v0.w * inv,
                v1.x * inv, v1.y * inv, v1.z * inv, v1.w * inv};

  union { __hip_bfloat16 h[8]; uint4 u4; } pk;
  float sv = 0.f, rv = 0.f;
#pragma unroll
  for (int i = 0; i < 8; ++i) {
    pk.h[i] = __float2bfloat16(y[i]);
    sv += y[i] * y[i];
    rv += y[i];
  }
  ((uint4*)(Y + (size_t)rid * DIM))[lane] = pk.u4;

#pragma unroll
  for (int o = 1; o < 64; o <<= 1) {
    sv += __shfl_xor(sv, o, 64);
    rv += __shfl_xor(rv, o, 64);
  }
  if (lane == 0) {
    (is_low ? s_l : s_e)[row] = sv;
    (is_low ? r_l : r_e)[row] = rv;
  }
}

// ---------------------------------------------------------------------------
// Symmetric fused MFMA kernel, round 9: low-register 512-thread reshape.
// Register history: R6 need 244 under 256-cap: OK (80us). R7 need ~184 vs
// 128-cap: 205 MB spill. R8 need ~184 vs 170-cap: 129 MB spill. Budget is
// UNIFIED arch+AGPR. R9 shrinks need to ~110 (acc 32 AGPR + dl-f16 16 +
// frags 24 + addr ~10 + misc) and uses __launch_bounds__(512,4): cap 128,
// 2 blocks/CU = 16 waves/CU (2x R6).
// Grid: 561 blocks -> (br,bc) upper triangle, tile 128x128 (stride 127).
// 8 waves in 4x2 (wr=wid>>1 rows 32*wr.., wc=wid&1 cols 64*wc..),
// wave tile 32x64, ONE matrix at a time.
// Phase m=0 (low): K-loop -> distances -> packed f16. m=1 (emb): de in acc.
// K-loop: BK=64, 8 iters/phase, stage A(128 rows)+B(128 cols) = 32 KB via
//   global_load_lds w=16; K-chunk XOR-swizzled by row&7 on the GLOBAL side
//   (zero bank conflicts, verified R7/R8). Diagonal blocks (br==bc) skip
//   B staging and read B frags from the A segment (same rows).
// C frag mapping (m89/m91): col(j)=lane&15, row(i)=(lane>>4)*4+reg.
// ---------------------------------------------------------------------------
__global__ __launch_bounds__(512, 4) void fused_sym_kernel(
    const __hip_bfloat16* __restrict__ Y,
    const float* __restrict__ s_l, const float* __restrict__ r_l,
    const float* __restrict__ s_e, const float* __restrict__ r_e,
    float* __restrict__ out) {
  __shared__ __align__(16) __hip_bfloat16 lds[16384];  // 32 KB staging
  __shared__ float hand_d[4][32][2];    // col-64 dl/de per wr row-group
  __shared__ float hand_t[4][128][2];   // row-32*wr dl/de ([wr-1] slot)
  __shared__ float sred[8];

  // decode upper-triangle block id
  int rem = blockIdx.x, br = 0;
  while (rem >= NT - br) { rem -= NT - br; ++br; }
  const int bc = br + rem;
  const bool diag = (br == bc);

  const int tid = threadIdx.x;
  const int lane = tid & 63;
  const int wid = tid >> 6;          // 0..7
  const int wr = wid >> 1;           // 0..3: rows 32*wr..32*wr+31
  const int wc = wid & 1;            // 0..1: cols 64*wc..64*wc+63
  const int quad = lane >> 4, cpos = lane & 15;
  const int sw = cpos & 7;
  const int r0 = br * TSTRIDE, c0 = bc * TSTRIDE;

  // staging: 2048 slots of 16B; thread owns slot c = tid + 512*s, s=0..3.
  // c<1024: A local row c>>3; else B local col (c-1024)>>3.
  // stored global K-chunk = (c&7) ^ (row&7)  [swizzle].
  int goff[4];
#pragma unroll
  for (int s = 0; s < 4; ++s) {
    const int c = tid + 512 * s;
    int base;
    if (c < 1024) base = min(r0 + (c >> 3), BROWS - 1) * DIM;
    else          base = min(c0 + ((c - 1024) >> 3), BROWS - 1) * DIM;
    goff[s] = base + (((c & 7) ^ ((c >> 3) & 7)) << 3);
  }

  // frag base offsets (elems); chunk = ((kk*4+quad)^sw)*8 added per read
  const int abase0 = (32 * wr + cpos) * 64;              // u stride 16*64
  const int bbase0 = (diag ? 0 : 8192) + (64 * wc + cpos) * 64;  // v stride 16*64

  const float epst = (float)DIM * 1e-6f * 1e-6f;
  f32x4 acc[2][4];
  f16x4 dlh[2][4];

#pragma unroll
  for (int m = 0; m < 2; ++m) {
    const __hip_bfloat16* Ym = Y + m * YEMB_E;
#pragma unroll
    for (int u = 0; u < 2; ++u)
#pragma unroll
      for (int v = 0; v < 4; ++v) acc[u][v] = (f32x4)(0.f);

    for (int it = 0; it < 8; ++it) {
      const int k0 = it * 64;
#pragma unroll
      for (int s = 0; s < 4; ++s) {
        if (s < 2 || !diag)
          __builtin_amdgcn_global_load_lds(
              (const __attribute__((address_space(1))) void*)(Ym + goff[s] + k0),
              (__attribute__((address_space(3))) void*)(lds + (tid + 512 * s) * 8),
              16, 0, 0);
      }
      __syncthreads();

#pragma unroll
      for (int kk = 0; kk < 2; ++kk) {
        const int ch = ((kk * 4 + quad) ^ sw) << 3;
        bf16x8 a[2], b[4];
#pragma unroll
        for (int u = 0; u < 2; ++u)
          a[u] = *(const bf16x8*)&lds[abase0 + u * 1024 + ch];
#pragma unroll
        for (int v = 0; v < 4; ++v)
          b[v] = *(const bf16x8*)&lds[bbase0 + v * 1024 + ch];
#pragma unroll
        for (int u = 0; u < 2; ++u)
#pragma unroll
          for (int v = 0; v < 4; ++v)
            acc[u][v] = __builtin_amdgcn_mfma_f32_16x16x32_bf16(
                a[u], b[v], acc[u][v], 0, 0, 0);
      }
      __syncthreads();
    }

    // transform acc -> distances for this matrix
    const float* sp = m ? s_e : s_l;
    const float* rp = m ? r_e : r_l;
#pragma unroll
    for (int v = 0; v < 4; ++v) {
      const int j = min(c0 + 64 * wc + 16 * v + cpos, BROWS - 1);
      const float sj = sp[j], rj = rp[j];
#pragma unroll
      for (int u = 0; u < 2; ++u) {
        float d[4];
#pragma unroll
        for (int r = 0; r < 4; ++r) {
          const int i = min(r0 + 32 * wr + 16 * u + 4 * quad + r, BROWS - 1);
          const float sq = sp[i] + sj - 2.f * acc[u][v][r] +
                           2e-6f * (rp[i] - rj) + epst;
          d[r] = sqrtf(fmaxf(sq, 0.f));
        }
        if (m == 0) {
          dlh[u][v] = (f16x4){(_Float16)d[0], (_Float16)d[1],
                              (_Float16)d[2], (_Float16)d[3]};
        } else {
          acc[u][v] = (f32x4){d[0], d[1], d[2], d[3]};
        }
      }
    }
  }
  // now: dl (f16) in dlh, de (f32) in acc

  // ---- publish cross-wave boundary values ----
  if (wc == 1 && cpos == 0) {   // tile col 64 for this wr's 32 rows
#pragma unroll
    for (int u = 0; u < 2; ++u)
#pragma unroll
      for (int r = 0; r < 4; ++r) {
        hand_d[wr][16 * u + 4 * quad + r][0] = (float)dlh[u][0][r];
        hand_d[wr][16 * u + 4 * quad + r][1] = acc[u][0][r];
      }
  }
  if (quad == 0 && wr >= 1) {   // tile row 32*wr (u=0,r=0) for 64 cols
#pragma unroll
    for (int v = 0; v < 4; ++v) {
      hand_t[wr - 1][64 * wc + 16 * v + cpos][0] = (float)dlh[0][v][0];
      hand_t[wr - 1][64 * wc + 16 * v + cpos][1] = acc[0][v][0];
    }
  }
  __syncthreads();

  float sum = 0.f;

  // ---- pass 1: direct terms (i in rows, pair cols j,j+1) ----
  const int srcin = (lane & 48) | ((cpos + 1) & 15);
#pragma unroll
  for (int u = 0; u < 2; ++u)
#pragma unroll
    for (int r = 0; r < 4; ++r) {
      const int trow = 32 * wr + 16 * u + 4 * quad + r;
      const int i = r0 + trow;
      const bool rowok = (trow <= 126) && (i <= BROWS - 2);
#pragma unroll
      for (int v = 0; v < 4; ++v) {
        const float dl1 = (float)dlh[u][v][r], de1 = acc[u][v][r];
        float dl2 = __shfl(dl1, srcin, 64);
        float de2 = __shfl(de1, srcin, 64);
        if (v < 3) {
          const float dlb = __shfl((float)dlh[u][v + 1][r], lane & 48, 64);
          const float deb = __shfl(acc[u][v + 1][r], lane & 48, 64);
          if (cpos == 15) { dl2 = dlb; de2 = deb; }
        } else if (cpos == 15 && wc == 0) {
          dl2 = hand_d[wr][16 * u + 4 * quad + r][0];
          de2 = hand_d[wr][16 * u + 4 * quad + r][1];
        }
        const int tcol = 64 * wc + 16 * v + cpos;
        const int j = c0 + tcol;
        if (rowok && tcol <= 126 && j <= BROWS - 3) {
          const float aa = dl1 - dl2, bb = de1 - de2;
          const float coeff = (float)((aa > 0.f) - (aa < 0.f)) -
                              (float)((bb > 0.f) - (bb < 0.f));
          sum += coeff * (de2 - de1);
        }
      }
    }

  // ---- pass 2: transposed terms (i in cols, pair rows j,j+1), off-diag only ----
  if (!diag) {
#pragma unroll
    for (int u = 0; u < 2; ++u)
#pragma unroll
      for (int v = 0; v < 4; ++v) {
        const int tcol = 64 * wc + 16 * v + cpos;
        const int ii = c0 + tcol;
        const bool colok = (tcol <= 126) && (ii <= BROWS - 2);
        const float dlv[4] = {(float)dlh[u][v][0], (float)dlh[u][v][1],
                              (float)dlh[u][v][2], (float)dlh[u][v][3]};
#pragma unroll
        for (int r = 0; r < 3; ++r) {
          const int trow = 32 * wr + 16 * u + 4 * quad + r;
          const int jj = r0 + trow;
          if (colok && trow <= 126 && jj <= BROWS - 3) {
            const float aa = dlv[r] - dlv[r + 1];
            const float bb = acc[u][v][r] - acc[u][v][r + 1];
            const float coeff = (float)((aa > 0.f) - (aa < 0.f)) -
                                (float)((bb > 0.f) - (bb < 0.f));
            sum += coeff * (acc[u][v][r + 1] - acc[u][v][r]);
          }
        }
        {  // r == 3 boundary: next row in another quad / u / wave
          const int trow = 32 * wr + 16 * u + 4 * quad + 3;
          const int jj = r0 + trow;
          const float dlq = __shfl(dlv[0], (lane + 16) & 63, 64);
          const float deq = __shfl(acc[u][v][0], (lane + 16) & 63, 64);
          const float dlu = __shfl((float)dlh[u ? u : 1][v][0], cpos, 64);
          const float deu = __shfl(acc[u ? u : 1][v][0], cpos, 64);
          float dl2, de2;
          if (quad < 3)      { dl2 = dlq; de2 = deq; }
          else if (u == 0)   { dl2 = dlu; de2 = deu; }
          else               { dl2 = hand_t[wr][tcol][0];   // wr==3 filtered
                               de2 = hand_t[wr][tcol][1]; }
          if (colok && trow <= 126 && jj <= BROWS - 3) {
            const float dl1 = dlv[3], de1 = acc[u][v][3];
            const float aa = dl1 - dl2, bb = de1 - de2;
            const float coeff = (float)((aa > 0.f) - (aa < 0.f)) -
                                (float)((bb > 0.f) - (bb < 0.f));
            sum += coeff * (de2 - de1);
          }
        }
      }
  }

  // ---- reduce + atomic ----
#pragma unroll
  for (int o = 32; o; o >>= 1) sum += __shfl_down(sum, o, 64);
  if (lane == 0) sred[wid] = sum;
  __syncthreads();
  if (tid == 0) {
    const float scale = 1.0f / ((float)(BROWS - 1) * (float)(BROWS - 2));
    float t = 0.f;
#pragma unroll
    for (int w = 0; w < 8; ++w) t += sred[w];
    atomicAdd(out, t * scale);
  }
}

// ===========================================================================
extern "C" void kernel_launch(void* const* d_in, const int* in_sizes, int n_in,
                              void* d_out, int out_size, void* d_ws,
                              size_t ws_size, hipStream_t stream) {
  const float* low = (const float*)d_in[0];
  const float* emb = (const float*)d_in[1];
  float* out = (float*)d_out;

  // ws: Y (2*4096*512 bf16 = 8 MB) then s_l, r_l, s_e, r_e (4096 f32 each)
  __hip_bfloat16* Y = (__hip_bfloat16*)d_ws;
  float* s_l = (float*)(Y + 2 * (size_t)BROWS * DIM);
  float* r_l = s_l + BROWS;
  float* s_e = r_l + BROWS;
  float* r_e = s_e + BROWS;

  prep3_kernel<<<2 * BROWS / 4, 256, 0, stream>>>(low, emb, Y, s_l, r_l, s_e, r_e, out);
  fused_sym_kernel<<<NT * (NT + 1) / 2, 512, 0, stream>>>(Y, s_l, r_l, s_e, r_e, out);
}